// Round 6
// baseline (433.628 us; speedup 1.0000x reference)
//
#include <hip/hip_runtime.h>
#include <hip/hip_bf16.h>
#include <stdint.h>

#define T_ 2048
#define H_ 1024
#define I_ 2048
#define E_ 8
#define NE_ 9            // 8 routed + 1 shared (virtual expert)

typedef __attribute__((ext_vector_type(8))) short bf16x8;
typedef __attribute__((ext_vector_type(4))) float f32x4;

__device__ __forceinline__ unsigned short f2bf(float f) {
  unsigned int u; __builtin_memcpy(&u, &f, 4);
  u = (u + 0x7fffu + ((u >> 16) & 1u)) >> 16;
  return (unsigned short)u;
}
__device__ __forceinline__ void cvt2(float a, float b, unsigned short* dst) {
  __hip_bfloat162 h = __float22bfloat162_rn(float2{a, b});
  __builtin_memcpy(dst, &h, 4);
}
// async global->LDS DMA, 16B per lane; LDS dest = wave-uniform base + lane*16
__device__ __forceinline__ void gll16(const void* g, void* l) {
  __builtin_amdgcn_global_load_lds((const __attribute__((address_space(1))) void*)g,
                                   (__attribute__((address_space(3))) void*)l, 16, 0, 0);
}

// ---------------- front: router (blocks 0..511) + weight pack (512..5119) ----------------
// packW: each block converts an 8-row slab of one fp32 [K][N] matrix into the
// blocked bf16 layout. Reads are contiguous 4KB row segments (streaming);
// LDS [8][1024] fp32 staging; writes 1KB-contiguous per 16 threads.
#define RTR_BLKS 512
#define PW01_BLKS 2304   // 18 matrices (grp0/1: K=1024,N=2048) * 128 slabs
#define PW2_BLKS 2304    // 9 matrices (grp2:  K=2048,N=1024) * 256 slabs
#define FRONT_GRID (RTR_BLKS + PW01_BLKS + PW2_BLKS)
__global__ __launch_bounds__(256) void k_front(
    const float* __restrict__ x, const float* __restrict__ rw,
    int* __restrict__ topi, float* __restrict__ topw,
    int* __restrict__ cnt, float* __restrict__ psum,
    float* __restrict__ outz,
    const float* __restrict__ eg, const float* __restrict__ eu, const float* __restrict__ ed,
    const float* __restrict__ sg, const float* __restrict__ su, const float* __restrict__ sd,
    unsigned short* __restrict__ wgp, unsigned short* __restrict__ wup,
    unsigned short* __restrict__ wdp) {
  __shared__ float smem[8192];        // 32KB: router lrw OR packW slab
  __shared__ float sprob[4][9];
  __shared__ int shist[8];
  int tid = threadIdx.x;
  int bz = blockIdx.x;

  if (bz < RTR_BLKS) {
    // ---- router ----
    // zero out-slice: 512 blocks x 16KB
    {
      float4 zf = {0.f, 0.f, 0.f, 0.f};
      float4* ob = (float4*)(outz + (size_t)bz * 4096);
#pragma unroll
      for (int i = 0; i < 4; i++) ob[i * 256 + tid] = zf;
    }
    if (tid < 8) shist[tid] = 0;
#pragma unroll
    for (int i = 0; i < 8; i++) {
      int idx = i * 256 + tid;          // float4 index over 2048
      float4 v = ((const float4*)rw)[idx];
      int f = idx * 4; int h = f >> 3; int e0 = f & 7;
      smem[(e0 + 0) * H_ + h] = v.x;
      smem[(e0 + 1) * H_ + h] = v.y;
      smem[(e0 + 2) * H_ + h] = v.z;
      smem[(e0 + 3) * H_ + h] = v.w;
    }
    __syncthreads();
    int w = tid >> 6, lane = tid & 63;
    int t = bz * 4 + w;
    const float* xp = x + (size_t)t * H_ + lane;
    float xr[16];
#pragma unroll
    for (int j = 0; j < 16; j++) xr[j] = xp[j * 64];
    float acc[E_];
#pragma unroll
    for (int e = 0; e < E_; e++) acc[e] = 0.f;
#pragma unroll
    for (int j = 0; j < 16; j++) {
      float xf = xr[j];
      const float* wp = &smem[j * 64 + lane];
#pragma unroll
      for (int e = 0; e < E_; e++) acc[e] += xf * wp[e * H_];
    }
#pragma unroll
    for (int off = 32; off >= 1; off >>= 1) {
#pragma unroll
      for (int e = 0; e < E_; e++) acc[e] += __shfl_xor(acc[e], off, 64);
    }
    if (lane == 0) {
      float m = acc[0];
#pragma unroll
      for (int e = 1; e < E_; e++) m = fmaxf(m, acc[e]);
      float p[E_], s = 0.f;
#pragma unroll
      for (int e = 0; e < E_; e++) { p[e] = expf(acc[e] - m); s += p[e]; }
      float inv = 1.f / s;
#pragma unroll
      for (int e = 0; e < E_; e++) p[e] *= inv;
      float lse = m + logf(s);
#pragma unroll
      for (int e = 0; e < E_; e++) sprob[w][e] = p[e];
      sprob[w][8] = lse * lse;
      int i0 = 0;
#pragma unroll
      for (int e = 1; e < E_; e++) if (p[e] > p[i0]) i0 = e;
      int i1 = (i0 == 0) ? 1 : 0;
#pragma unroll
      for (int e = 0; e < E_; e++) if (e != i0 && e != i1 && p[e] > p[i1]) i1 = e;
      float w0 = p[i0], w1 = p[i1], wsum = w0 + w1;
      topi[t * 2] = i0; topi[t * 2 + 1] = i1;
      topw[t * 2] = w0 / wsum; topw[t * 2 + 1] = w1 / wsum;
      atomicAdd(&shist[i0], 1);
      atomicAdd(&shist[i1], 1);
    }
    __syncthreads();
    if (tid < 8 && shist[tid]) atomicAdd(&cnt[tid], shist[tid]);
    if (tid < 9)
      atomicAdd(&psum[tid], sprob[0][tid] + sprob[1][tid] + sprob[2][tid] + sprob[3][tid]);
    return;
  }

  // ---- packW ----
  int pb = bz - RTR_BLKS;
  const float* src; unsigned short* dst;
  int K, N, slab;
  if (pb < PW01_BLKS) {
    int mat = pb >> 7;             // 0..17
    slab = pb & 127;
    int grp = mat / NE_, e = mat % NE_;
    K = H_; N = I_;
    if (grp == 0) { src = (e < E_) ? eg + (size_t)e * H_ * I_ : sg; dst = wgp + (size_t)e * H_ * I_; }
    else          { src = (e < E_) ? eu + (size_t)e * H_ * I_ : su; dst = wup + (size_t)e * H_ * I_; }
  } else {
    int pb2 = pb - PW01_BLKS;
    int e = pb2 >> 8;              // 0..8
    slab = pb2 & 255;
    K = I_; N = H_;
    src = (e < E_) ? ed + (size_t)e * I_ * H_ : sd;
    dst = wdp + (size_t)e * I_ * H_;
  }
  int k0 = slab * 8;
  int kt = k0 >> 5, q = (k0 >> 3) & 3;
  int npass = N >> 10;             // 2 for N=2048, 1 for N=1024
  int l_nt = tid >> 4;             // 0..15
  int nn0 = (tid & 15) * 4;        // 0,4,..60

  for (int p = 0; p < npass; ++p) {
    const float* srcp = src + (size_t)k0 * N + p * 1024;
    // phase 1: stream 8 rows x 1024 cols into LDS (contiguous 1KB per wave-instr)
#pragma unroll
    for (int i = 0; i < 8; i++) {
      float4 v = *(const float4*)(srcp + (size_t)i * N + 4 * tid);
      *(float4*)&smem[i * 1024 + 4 * tid] = v;
    }
    __syncthreads();
    // phase 2: transpose-convert: thread -> (l_nt, nn0..nn0+3) x (j=0..7)
    unsigned short obuf[32];
#pragma unroll
    for (int jj = 0; jj < 4; jj++) {
      float4 a = *(const float4*)&smem[(2 * jj) * 1024 + l_nt * 64 + nn0];
      float4 b = *(const float4*)&smem[(2 * jj + 1) * 1024 + l_nt * 64 + nn0];
      cvt2(a.x, b.x, &obuf[0 * 8 + 2 * jj]);
      cvt2(a.y, b.y, &obuf[1 * 8 + 2 * jj]);
      cvt2(a.z, b.z, &obuf[2 * 8 + 2 * jj]);
      cvt2(a.w, b.w, &obuf[3 * 8 + 2 * jj]);
    }
    int nt = p * 16 + l_nt;
    size_t base = ((size_t)nt * (K / 32) + kt) * 2048 + q * 512 + (size_t)nn0 * 8;
#pragma unroll
    for (int ci = 0; ci < 4; ci++)
      *(bf16x8*)&dst[base + ci * 8] = *(bf16x8*)&obuf[ci * 8];
    __syncthreads();   // LDS reused next pass
  }
}

// ---------------- sched2: parallel fill (9 blocks) ----------------
// block e<8: ordered emit of expert e's tokens via prefix scan.
// block 8: shared-expert list + poffs + cnt[8] + aux.
__global__ __launch_bounds__(256) void k_sched2(
    const int* __restrict__ topi, const float* __restrict__ topw,
    int* __restrict__ cnt, int* __restrict__ poffs, const float* __restrict__ psum,
    float* __restrict__ out_aux,
    int* __restrict__ tok, float* __restrict__ wgt) {
  int tid = threadIdx.x;
  int e = blockIdx.x;
  // local poffs from cnt (deterministic; all blocks compute identically)
  int pol[NE_ + 1];
  {
    int po = 0;
#pragma unroll
    for (int i = 0; i < NE_; i++) {
      pol[i] = po;
      int ce = (i < E_) ? cnt[i] : T_;
      po += ((ce + 127) >> 7) << 7;
    }
    pol[NE_] = po;
  }
  if (e == E_) {
    // shared expert: identity fill
    int p8 = pol[E_];
    for (int t = tid; t < T_; t += 256) { tok[p8 + t] = t; wgt[p8 + t] = 1.f; }
    if (tid == 0) {
#pragma unroll
      for (int i = 0; i <= NE_; i++) poffs[i] = pol[i];
      cnt[E_] = T_;
      float lb = 0.f;
#pragma unroll
      for (int i = 0; i < E_; i++)
        lb += ((float)cnt[i] / 4096.f) * (psum[i] / 2048.f);
      out_aux[0] = 0.01f * 8.f * lb + 0.001f * (psum[8] / 2048.f);
    }
    return;
  }
  // routed expert e: each thread scans 8 tokens, prefix-scan, ordered emit
  __shared__ int sc2[256];
  int t0 = tid * 8;
  int m = 0;
  int e0v[8], e1v[8];
#pragma unroll
  for (int i = 0; i < 8; i++) {
    e0v[i] = topi[(t0 + i) * 2];
    e1v[i] = topi[(t0 + i) * 2 + 1];
    m += (e0v[i] == e) + (e1v[i] == e);
  }
  sc2[tid] = m;
  __syncthreads();
  for (int s = 1; s < 256; s <<= 1) {
    int v = (tid >= s) ? sc2[tid - s] : 0;
    __syncthreads();
    sc2[tid] += v;
    __syncthreads();
  }
  int pos = pol[e] + sc2[tid] - m;
#pragma unroll
  for (int i = 0; i < 8; i++) {
    int tk = t0 + i;
    if (e0v[i] == e) { tok[pos] = tk; wgt[pos] = topw[tk * 2]; pos++; }
    if (e1v[i] == e) { tok[pos] = tk; wgt[pos] = topw[tk * 2 + 1]; pos++; }
  }
}

// ---------------- packA: gather x rows -> bf16 blocked A [rt][kt][q][m][8] ----------------
__global__ __launch_bounds__(256) void k_packA(
    const float* __restrict__ x, const int* __restrict__ cnt,
    const int* __restrict__ poffs, const int* __restrict__ tok,
    unsigned short* __restrict__ apack) {
  int kc = blockIdx.x, mt = blockIdx.y, e = blockIdx.z;
  int cnt_e = cnt[e];
  if (mt * 128 >= cnt_e) return;
  int po = poffs[e];
  int rt = (po >> 7) + mt;
  int t = threadIdx.x;
  int m = t & 127, qh = t >> 7;
  int atok = tok[po + min(mt * 128 + m, cnt_e - 1)];
  const float* arow = x + (size_t)atok * H_;
  size_t abase = (size_t)rt * 32 * 4096;
#pragma unroll
  for (int ki = 0; ki < 4; ki++) {
    int kt = kc * 4 + ki;
#pragma unroll
    for (int qo = 0; qo < 2; qo++) {
      int q = qh + qo * 2;
      const float* s = arow + kt * 32 + q * 8;
      float4 v0 = *(const float4*)s, v1 = *(const float4*)(s + 4);
      unsigned short t8[8];
      cvt2(v0.x, v0.y, t8); cvt2(v0.z, v0.w, t8 + 2);
      cvt2(v1.x, v1.y, t8 + 4); cvt2(v1.z, v1.w, t8 + 6);
      *(bf16x8*)&apack[abase + (size_t)kt * 4096 + q * 1024 + m * 8] = *(bf16x8*)t8;
    }
  }
}

// ---------------- GEMM1: h = silu(x*Wg)*(x*Wu) ---------------- (round-1 exact)
#define G1_GRID 1792   // 56 rt-slots * 32 nt, multiple of 8
__global__ __launch_bounds__(256) void k_gemm1(
    const unsigned short* __restrict__ apack,
    const unsigned short* __restrict__ wgp, const unsigned short* __restrict__ wup,
    const int* __restrict__ cnt, const int* __restrict__ poffs,
    unsigned short* __restrict__ hbuf) {
  int lin = blockIdx.x;
  int s = (lin & 7) * (G1_GRID / 8) + (lin >> 3);   // bijective XCD chunk swizzle
  int rt = s >> 5, nt = s & 31;
  int rtTotal = poffs[NE_] >> 7;
  if (rt >= rtTotal) return;
  int ro = rt << 7;
  int e = 0;
#pragma unroll
  for (int i = 1; i < NE_; i++) if (poffs[i] <= ro) e = i;
  int po = poffs[e];
  int cnt_e = cnt[e];
  int mt = (ro - po) >> 7;

  __shared__ __align__(16) unsigned short As[2][4096];   // [q][m][8]
  __shared__ __align__(16) unsigned short BgS[2][2048];  // [q][nn][8]
  __shared__ __align__(16) unsigned short BuS[2][2048];

  int tid = threadIdx.x;
  int lane = tid & 63, w = tid >> 6;
  int quad = lane >> 4, l15 = lane & 15;
  int wm = w >> 1, wn = w & 1;

  const unsigned short* abase = apack + (size_t)rt * 32 * 4096;
  const unsigned short* bgb = wgp + (size_t)e * H_ * I_ + (size_t)nt * 32 * 2048;
  const unsigned short* bub = wup + (size_t)e * H_ * I_ + (size_t)nt * 32 * 2048;

  f32x4 zero = {0.f, 0.f, 0.f, 0.f};
  f32x4 accg[4][2], accu[4][2];
#pragma unroll
  for (int mi = 0; mi < 4; mi++)
#pragma unroll
    for (int ni = 0; ni < 2; ni++) { accg[mi][ni] = zero; accu[mi][ni] = zero; }

#define STAGE1(kt, b) do { \
    const unsigned short* asrc = abase + (size_t)(kt) * 4096 + w * 1024 + lane * 8; \
    gll16(asrc, &As[b][w * 1024]); \
    gll16(asrc + 512, &As[b][w * 1024 + 512]); \
    gll16(bgb + (size_t)(kt) * 2048 + w * 512 + lane * 8, &BgS[b][w * 512]); \
    gll16(bub + (size_t)(kt) * 2048 + w * 512 + lane * 8, &BuS[b][w * 512]); \
  } while (0)

  STAGE1(0, 0);
  __syncthreads();   // drains vmcnt(0): buf0 ready
  for (int kt = 0; kt < 32; kt++) {
    int cur = kt & 1;
    if (kt < 31) STAGE1(kt + 1, cur ^ 1);   // in flight under the compute below
    bf16x8 af[4];
#pragma unroll
    for (int mi = 0; mi < 4; mi++)
      af[mi] = *(const bf16x8*)&As[cur][quad * 1024 + (wm * 64 + mi * 16 + l15) * 8];
#pragma unroll
    for (int ni = 0; ni < 2; ni++) {
      bf16x8 bg = *(const bf16x8*)&BgS[cur][quad * 512 + (wn * 32 + ni * 16 + l15) * 8];
      bf16x8 bu = *(const bf16x8*)&BuS[cur][quad * 512 + (wn * 32 + ni * 16 + l15) * 8];
#pragma unroll
      for (int mi = 0; mi < 4; mi++) {
        accg[mi][ni] = __builtin_amdgcn_mfma_f32_16x16x32_bf16(af[mi], bg, accg[mi][ni], 0, 0, 0);
        accu[mi][ni] = __builtin_amdgcn_mfma_f32_16x16x32_bf16(af[mi], bu, accu[mi][ni], 0, 0, 0);
      }
    }
    __syncthreads();   // next buffer staged + everyone done reading cur
  }
#undef STAGE1

  // epilogue: silu(g)*u -> hbuf in gemm2's packed-A layout [rt][kt2][q2][m][8]
  size_t hbase = (size_t)rt * 64 * 4096;
  int rem = cnt_e - mt * 128;
#pragma unroll
  for (int ni = 0; ni < 2; ni++) {
    int cc = nt * 64 + wn * 32 + ni * 16 + l15;
    size_t cb = hbase + (size_t)(cc >> 5) * 4096 + (size_t)((cc >> 3) & 3) * 1024 + (cc & 7);
#pragma unroll
    for (int mi = 0; mi < 4; mi++)
#pragma unroll
      for (int r = 0; r < 4; r++) {
        int row = wm * 64 + mi * 16 + quad * 4 + r;
        if (row < rem) {
          float g = accg[mi][ni][r], u = accu[mi][ni][r];
          float sv = g / (1.f + __expf(-g));
          hbuf[cb + (size_t)row * 8] = f2bf(sv * u);
        }
      }
  }
}

// ---------------- GEMM2: out += w * (h * Wd); K-split x2, dbuf, swizzled ---------------- (round-1 exact)
#define G2_GRID 896    // 56 rt-slots * 8 nt * 2 khalf, multiple of 8
__global__ __launch_bounds__(256) void k_gemm2(
    const unsigned short* __restrict__ hbuf, const unsigned short* __restrict__ wdp,
    const int* __restrict__ cnt, const int* __restrict__ poffs,
    const int* __restrict__ tok, const float* __restrict__ wgt,
    float* __restrict__ out) {
  int lin = blockIdx.x;
  int s = (lin & 7) * (G2_GRID / 8) + (lin >> 3);   // bijective XCD chunk swizzle
  int rt = s >> 4;
  int r4 = s & 15;
  int nt = r4 >> 1, kh = r4 & 1;
  int rtTotal = poffs[NE_] >> 7;
  if (rt >= rtTotal) return;
  int ro = rt << 7;
  int e = 0;
#pragma unroll
  for (int i = 1; i < NE_; i++) if (poffs[i] <= ro) e = i;
  int po = poffs[e];
  int cnt_e = cnt[e];
  int mt = (ro - po) >> 7;

  __shared__ __align__(16) unsigned short As[2][4096];   // [q][m][8]
  __shared__ __align__(16) unsigned short BdS[2][4096];  // [h][q][nn][8]

  int tid = threadIdx.x;
  int lane = tid & 63, w = tid >> 6;
  int quad = lane >> 4, l15 = lane & 15;
  int wm = w >> 1, wn = w & 1;

  const unsigned short* abase = hbuf + (size_t)rt * 64 * 4096;
  const unsigned short* bb0 = wdp + (size_t)e * I_ * H_ + ((size_t)(2 * nt) * 64) * 2048;
  const unsigned short* bb1 = wdp + (size_t)e * I_ * H_ + ((size_t)(2 * nt + 1) * 64) * 2048;

  f32x4 zero = {0.f, 0.f, 0.f, 0.f};
  f32x4 acc[4][4];
#pragma unroll
  for (int mi = 0; mi < 4; mi++)
#pragma unroll
    for (int ni = 0; ni < 4; ni++) acc[mi][ni] = zero;

#define STAGE2(kt, b) do { \
    const unsigned short* asrc = abase + (size_t)(kt) * 4096 + w * 1024 + lane * 8; \
    gll16(asrc, &As[b][w * 1024]); \
    gll16(asrc + 512, &As[b][w * 1024 + 512]); \
    gll16(bb0 + (size_t)(kt) * 2048 + w * 512 + lane * 8, &BdS[b][w * 512]); \
    gll16(bb1 + (size_t)(kt) * 2048 + w * 512 + lane * 8, &BdS[b][2048 + w * 512]); \
  } while (0)

  int k0 = kh * 32;
  STAGE2(k0, 0);
  __syncthreads();
  for (int kk = 0; kk < 32; kk++) {
    int cur = kk & 1;
    if (kk < 31) STAGE2(k0 + kk + 1, cur ^ 1);
    bf16x8 af[4];
#pragma unroll
    for (int mi = 0; mi < 4; mi++)
      af[mi] = *(const bf16x8*)&As[cur][quad * 1024 + (wm * 64 + mi * 16 + l15) * 8];
#pragma unroll
    for (int ni = 0; ni < 4; ni++) {
      bf16x8 bd = *(const bf16x8*)&BdS[cur][wn * 2048 + quad * 512 + (ni * 16 + l15) * 8];
#pragma unroll
      for (int mi = 0; mi < 4; mi++)
        acc[mi][ni] = __builtin_amdgcn_mfma_f32_16x16x32_bf16(af[mi], bd, acc[mi][ni], 0, 0, 0);
    }
    __syncthreads();
  }
#undef STAGE2

  // epilogue: weighted fp32 atomic scatter (both k-halves accumulate)
  int rem = cnt_e - mt * 128;
#pragma unroll
  for (int mi = 0; mi < 4; mi++)
#pragma unroll
    for (int r = 0; r < 4; r++) {
      int row = wm * 64 + mi * 16 + quad * 4 + r;
      if (row < rem) {
        int g = po + mt * 128 + row;
        int tt = tok[g];
        float wt = wgt[g];
#pragma unroll
        for (int ni = 0; ni < 4; ni++) {
          int col = nt * 128 + wn * 64 + ni * 16 + l15;
          atomicAdd(&out[(size_t)tt * H_ + col], wt * acc[mi][ni][r]);
        }
      }
    }
}

extern "C" void kernel_launch(void* const* d_in, const int* in_sizes, int n_in,
                              void* d_out, int out_size, void* d_ws, size_t ws_size,
                              hipStream_t stream) {
  const float* x  = (const float*)d_in[0];
  const float* rw = (const float*)d_in[1];
  const float* eg = (const float*)d_in[2];
  const float* eu = (const float*)d_in[3];
  const float* ed = (const float*)d_in[4];
  const float* sg = (const float*)d_in[5];
  const float* su = (const float*)d_in[6];
  const float* sd = (const float*)d_in[7];
  float* out = (float*)d_out;
  char* ws = (char*)d_ws;

  int*   cnt  = (int*)(ws + 64);
  int*   poffs= (int*)(ws + 128);
  float* psum = (float*)(ws + 192);
  int*   topi = (int*)(ws + 4096);
  float* topw = (float*)(ws + 4096 + 16384);
  int*   tok  = (int*)(ws + 36864);
  float* wgt  = (float*)(ws + 66560);
  unsigned short* apack = (unsigned short*)(ws + 131072);                 // 14.68 MB
  unsigned short* hbuf  = (unsigned short*)(ws + 131072 + 14811136);      // 29.36 MB used max
  unsigned short* wgp   = (unsigned short*)(ws + 131072 + 14811136 + 29491200);
  unsigned short* wup   = (unsigned short*)((char*)wgp + (size_t)NE_ * H_ * I_ * 2);
  unsigned short* wdp   = (unsigned short*)((char*)wup + (size_t)NE_ * H_ * I_ * 2);

  hipMemsetAsync(ws, 0, 256, stream);   // cnt + poffs + psum accumulators

  k_front<<<FRONT_GRID, 256, 0, stream>>>(x, rw, topi, topw, cnt, psum, out,
                                          eg, eu, ed, sg, su, sd, wgp, wup, wdp);
  k_sched2<<<NE_, 256, 0, stream>>>(topi, topw, cnt, poffs, psum,
                                    out + (size_t)T_ * H_, tok, wgt);
  dim3 ga(8, 16, NE_);
  k_packA<<<ga, 256, 0, stream>>>(x, cnt, poffs, tok, apack);
  k_gemm1<<<G1_GRID, 256, 0, stream>>>(apack, wgp, wup, cnt, poffs, hbuf);
  k_gemm2<<<G2_GRID, 256, 0, stream>>>(hbuf, wdp, cnt, poffs, tok, wgt, out);
}